// Round 2
// baseline (281.676 us; speedup 1.0000x reference)
//
#include <hip/hip_runtime.h>

// T=2000 frames, B=64 batch, C=256 vocab, L=200 targets.
#define T_FRAMES 2000
#define BATCH    64
#define CVOC     256
#define LTGT     200
#define EPAD     200                  // emit row stride in HALVES (400 B, dense)
#define SEG      20                   // dp: rows per register segment (r5-proven)
#define NSEG     100                  // SEG*NSEG covers t=1..2000 (t=2000 discarded)
#define NEG_INF  (-1e30f)
#define INV_LN2  1.4426950408889634f
#define LN2      0.6931471805599453f
// emit stores p * 2^14 so every fp16 value is NORMAL (p in [~e^-12, 0.6] ->
// scaled [~0.1, 8192]); uniform 2^-12 relative rounding error, no subnormal
// tail. The scale is STORAGE-ONLY: the DP descales on load (e * 2^-14) so the
// recurrence sees plain probabilities (r5-proven decay dynamics; round-1's
// in-DP scale overflowed f32 at activation fronts -> inf).
#define SCALE_LOG2 14.0f
#define DESCALE    (1.0f / 16384.0f)

// Raw v_exp_f32 (2^x) / v_log_f32 (log2 x). __exp2f/__log2f collide with glibc
// reserved names in the -x hip TU — use the amdgcn builtins.
#if __has_builtin(__builtin_amdgcn_exp2f)
__device__ __forceinline__ float fexp2(float x) { return __builtin_amdgcn_exp2f(x); }
#else
__device__ __forceinline__ float fexp2(float x) { return exp2f(x); }
#endif
#if __has_builtin(__builtin_amdgcn_logf)
__device__ __forceinline__ float flog2(float x) { return __builtin_amdgcn_logf(x); }
#else
__device__ __forceinline__ float flog2(float x) { return log2f(x); }
#endif

// 4 packed fp16 emissions, 8-byte aligned so loads are global_load_dwordx2.
struct __align__(8) H4 { _Float16 x, y, z, w; };

// ---------------------------------------------------------------------------
// DPP helpers.
// ---------------------------------------------------------------------------
// wave_shr:1 with 0-fill for lane 0 — 0 is the linear-domain identity.
__device__ __forceinline__ float dpp_shr1_zero(float v) {
    return __int_as_float(__builtin_amdgcn_update_dpp(
        0, __float_as_int(v), 0x138, 0xF, 0xF, true));
}
__device__ __forceinline__ int dpp_shr1_zero_i(int v) {
    return __builtin_amdgcn_update_dpp(0, v, 0x138, 0xF, 0xF, true);
}
template <int CTRL, int RMASK>
__device__ __forceinline__ float dpp_term(float v) {
    return __int_as_float(__builtin_amdgcn_update_dpp(
        0, __float_as_int(v), CTRL, RMASK, 0xF, true));
}
// wave max (exact for non-negative v; 0-fill is the identity), bcast via lane 63.
__device__ __forceinline__ float wave_max(float v) {
    v = fmaxf(v, dpp_term<0x111, 0xF>(v));   // row_shr:1
    v = fmaxf(v, dpp_term<0x112, 0xF>(v));   // row_shr:2
    v = fmaxf(v, dpp_term<0x114, 0xF>(v));   // row_shr:4
    v = fmaxf(v, dpp_term<0x118, 0xF>(v));   // row_shr:8
    v = fmaxf(v, dpp_term<0x142, 0xA>(v));   // row_bcast:15 -> rows 1,3
    v = fmaxf(v, dpp_term<0x143, 0xC>(v));   // row_bcast:31 -> rows 2,3
    return __int_as_float(__builtin_amdgcn_readlane(__float_as_int(v), 63));
}
__device__ __forceinline__ float wave_sum(float v) {
    v += dpp_term<0x111, 0xF>(v);
    v += dpp_term<0x112, 0xF>(v);
    v += dpp_term<0x114, 0xF>(v);
    v += dpp_term<0x118, 0xF>(v);
    v += dpp_term<0x142, 0xA>(v);
    v += dpp_term<0x143, 0xC>(v);
    return __int_as_float(__builtin_amdgcn_readlane(__float_as_int(v), 63));
}

// ---------------------------------------------------------------------------
// Kernel 1: fused log-softmax + target gather, storing SCALED LINEAR fp16
// probabilities: emit[b][t][l] = (_Float16)(exp2(log2 p + 14)).
// ---------------------------------------------------------------------------
__global__ __launch_bounds__(256) void emit_kernel(const float* __restrict__ x,
                                                   const int* __restrict__ targets,
                                                   _Float16* __restrict__ emit) {
    __shared__ float s[16][CVOC];                // 16 KB
    const int w = threadIdx.x >> 6;
    const int lane = threadIdx.x & 63;
    const int r0 = blockIdx.x * 16 + w * 4;      // this wave's 4 rows (r = t*64+b)
    const int li = (lane < 50) ? lane : 49;

    float4 v[4];
#pragma unroll
    for (int k = 0; k < 4; ++k)
        v[k] = ((const float4*)(x + (size_t)(r0 + k) * CVOC))[lane];
    int4 tg[4];
#pragma unroll
    for (int k = 0; k < 4; ++k)
        tg[k] = ((const int4*)(targets + ((r0 + k) & 63) * LTGT))[li];

    float lse2[4];
#pragma unroll
    for (int k = 0; k < 4; ++k) {
        v[k].x *= INV_LN2; v[k].y *= INV_LN2; v[k].z *= INV_LN2; v[k].w *= INV_LN2;
        float m = fmaxf(fmaxf(v[k].x, v[k].y), fmaxf(v[k].z, v[k].w));
        m = wave_max(m);
        float ss = fexp2(v[k].x - m) + fexp2(v[k].y - m) +
                   fexp2(v[k].z - m) + fexp2(v[k].w - m);
        ss = wave_sum(ss);
        lse2[k] = m + flog2(ss);
        ((float4*)&s[w * 4 + k][lane * 4])[0] = v[k];   // same-wave staging
    }

#pragma unroll
    for (int k = 0; k < 4; ++k) {
        if (lane < 50) {
            const int r = r0 + k;
            const int t = r >> 6;
            const int b = r & 63;
            const float sc = SCALE_LOG2 - lse2[k];
            H4 h;
            h.x = (_Float16)fexp2(s[w * 4 + k][tg[k].x] + sc);
            h.y = (_Float16)fexp2(s[w * 4 + k][tg[k].y] + sc);
            h.z = (_Float16)fexp2(s[w * 4 + k][tg[k].z] + sc);
            h.w = (_Float16)fexp2(s[w * 4 + k][tg[k].w] + sc);
            ((H4*)(emit + ((size_t)b * T_FRAMES + t) * EPAD))[lane] = h;
        }
    }
}

// ---------------------------------------------------------------------------
// Kernel 2: forward DP, LINEAR domain with PER-LANE power-of-2 scale.
// value[l] = z[l] * 2^A(lane). Z'[l] = E[l]*(Z[l]+Z[l-1]); the cross-lane
// term is rescaled with one v_ldexp_f32 per step. Per-lane renorm every 4
// steps; inactive lanes adopt the left neighbor's scale (front propagation).
// Emissions arrive as fp16 storing p*2^14; the 2^-14 descale is folded into
// the per-element cvt (off the serial z-chain), so the recurrence sees plain
// probabilities — exactly the r5-proven decay dynamics.
// Zero transcendentals in the step loop. r5-proven ping-pong skeleton.
// ---------------------------------------------------------------------------
__device__ __forceinline__ H4 ld_row(const _Float16* base, int t, int fi) {
    return ((const H4*)(base + (size_t)t * EPAD))[fi];
}

// Per-lane renorm (exact, power-of-2): bring lane max into [1,2).
// Inactive (all-zero) lanes adopt the left neighbor's (pre-renorm) scale.
__device__ __forceinline__ void renorm(float& z0, float& z1, float& z2, float& z3,
                                       int& A) {
    const float m4 = fmaxf(fmaxf(z0, z1), fmaxf(z2, z3));
    const int Ap = dpp_shr1_zero_i(A);             // left neighbor's A (lane0: 0)
    const bool act = (m4 > 0.0f);
    const int sh = act ? (127 - ((__float_as_int(m4) >> 23) & 255)) : 0;
    z0 = ldexpf(z0, sh); z1 = ldexpf(z1, sh);
    z2 = ldexpf(z2, sh); z3 = ldexpf(z3, sh);
    A = act ? (A - sh) : Ap;
}

__global__ __launch_bounds__(64, 1) void dp_kernel(const _Float16* __restrict__ emit,
                                                   float* __restrict__ part) {
    const int b = blockIdx.x;
    const int lane = threadIdx.x;
    const _Float16* base = emit + (size_t)b * T_FRAMES * EPAD;
    const int fi = (lane < 50) ? lane : 49;

    // init: alpha0[0] = E00 (descaled): z0 = E00 at lane 0, A = 0; normalize once.
    const float e00 = (float)base[0] * DESCALE;
    float z0 = (lane == 0) ? e00 : 0.0f;
    float z1 = 0.0f, z2 = 0.0f, z3 = 0.0f;
    int A = 0;
    renorm(z0, z1, z2, z3, A);

    float res = 1.0f;
    int resA = 0;

    H4 ebA[SEG], ebB[SEG];

#pragma unroll
    for (int j = 0; j < SEG; ++j)                 // segment 0 -> A
        ebA[j] = ld_row(base, 1 + j, fi);

    // One DP step; capture (res,resA) at t == 1999; per-lane renorm every 4.
    // fp16->f32 convert + 2^-14 descale are per-element independent (not on
    // the serial z-chain).
#define DP_STEP(e, tcur, j)                                           \
    {                                                                 \
        const float p  = dpp_shr1_zero(z3);                           \
        const int   Ap = dpp_shr1_zero_i(A);                          \
        const float pe = ldexpf(p, Ap - A);                           \
        const float e0 = (float)(e).x * DESCALE;                      \
        const float e1 = (float)(e).y * DESCALE;                      \
        const float e2 = (float)(e).z * DESCALE;                      \
        const float e3 = (float)(e).w * DESCALE;                      \
        const float n0 = e0 * (z0 + pe);                              \
        const float n1 = e1 * (z1 + z0);                              \
        const float n2 = e2 * (z2 + z1);                              \
        const float n3 = e3 * (z3 + z2);                              \
        z0 = n0; z1 = n1; z2 = n2; z3 = n3;                           \
        if ((tcur) == T_FRAMES - 1) { res = z3; resA = A; }           \
        if (((j) & 3) == 3) renorm(z0, z1, z2, z3, A);                \
    }

    // NOTE (r5-proven skeleton): segment 99, j=19 touches t=2000 — a 400 B
    // over-read past this batch's rows (covered by ws slack for b=63). Its
    // result is discarded: (res,resA) captured at t==1999 (j=18), before the
    // j=19 step and its renorm.
    for (int sp = 0; sp < NSEG; sp += 2) {
#pragma unroll
        for (int j = 0; j < SEG; ++j)             // segment sp+1 -> B
            ebB[j] = ld_row(base, 1 + (sp + 1) * SEG + j, fi);
#pragma unroll
        for (int j = 0; j < SEG; ++j)             // compute segment sp (A)
            DP_STEP(ebA[j], 1 + sp * SEG + j, j);
        if (sp + 2 < NSEG) {
#pragma unroll
            for (int j = 0; j < SEG; ++j)         // segment sp+2 -> A
                ebA[j] = ld_row(base, 1 + (sp + 2) * SEG + j, fi);
        }
#pragma unroll
        for (int j = 0; j < SEG; ++j)             // compute segment sp+1 (B)
            DP_STEP(ebB[j], 1 + (sp + 1) * SEG + j, j);
    }
#undef DP_STEP

    const float rz = __int_as_float(__builtin_amdgcn_readlane(__float_as_int(res), 49));
    const int rA = __builtin_amdgcn_readlane(resA, 49);
    if (lane == 0) part[b] = -((float)rA + flog2(rz)) * LN2;   // back to nats
}

// ---------------------------------------------------------------------------
// Kernel 3: mean over the 64 per-batch NLLs.
// ---------------------------------------------------------------------------
__global__ __launch_bounds__(64) void reduce_kernel(const float* __restrict__ part,
                                                    float* __restrict__ out) {
    float v = part[threadIdx.x];
#pragma unroll
    for (int s = 1; s < 64; s <<= 1) v += __shfl_xor(v, s, 64);
    if (threadIdx.x == 0) out[0] = v * (1.0f / BATCH);
}

// ===========================================================================
// Fallback path (round-1, natural-log domain, verified) if ws too small.
// ===========================================================================
__device__ __forceinline__ float lae(float a, float b) {
    float m = fmaxf(a, b);
    float d = fminf(a, b) - m;
    return m + __logf(1.0f + __expf(d));
}

__global__ __launch_bounds__(256) void lse_kernel(const float* __restrict__ x,
                                                  float* __restrict__ lse) {
    const int wave = threadIdx.x >> 6;
    const int lane = threadIdx.x & 63;
    const int r = blockIdx.x * 4 + wave;
    float4 v = ((const float4*)(x + (size_t)r * CVOC))[lane];
    float m = fmaxf(fmaxf(v.x, v.y), fmaxf(v.z, v.w));
#pragma unroll
    for (int s = 1; s < 64; s <<= 1) m = fmaxf(m, __shfl_xor(m, s, 64));
    float ssum = __expf(v.x - m) + __expf(v.y - m) + __expf(v.z - m) + __expf(v.w - m);
#pragma unroll
    for (int s = 1; s < 64; s <<= 1) ssum += __shfl_xor(ssum, s, 64);
    if (lane == 0) {
        const int t = r >> 6;
        const int b = r & 63;
        lse[b * T_FRAMES + t] = m + __logf(ssum);
    }
}

__global__ __launch_bounds__(64) void dp_slow_kernel(const float* __restrict__ x,
                                                     const int* __restrict__ targets,
                                                     const float* __restrict__ lse,
                                                     float* __restrict__ part) {
    __shared__ float s_lse[T_FRAMES];
    const int b = blockIdx.x;
    const int lane = threadIdx.x;
    for (int i = lane; i < T_FRAMES; i += 64) s_lse[i] = lse[b * T_FRAMES + i];
    const int* tg = targets + b * LTGT;
    const int l0 = lane * 4;
    const int i0 = tg[(l0 + 0 < LTGT) ? (l0 + 0) : (LTGT - 1)];
    const int i1 = tg[(l0 + 1 < LTGT) ? (l0 + 1) : (LTGT - 1)];
    const int i2 = tg[(l0 + 2 < LTGT) ? (l0 + 2) : (LTGT - 1)];
    const int i3 = tg[(l0 + 3 < LTGT) ? (l0 + 3) : (LTGT - 1)];
    const float* xb = x + b * CVOC;
    __syncthreads();
    float a0 = (lane == 0) ? (xb[i0] - s_lse[0]) : NEG_INF;
    float a1 = NEG_INF, a2 = NEG_INF, a3 = NEG_INF;
    const float* rA = xb + (size_t)1 * BATCH * CVOC;
    float pa0 = rA[i0], pa1 = rA[i1], pa2 = rA[i2], pa3 = rA[i3];
    const float* rB = xb + (size_t)2 * BATCH * CVOC;
    float pb0 = rB[i0], pb1 = rB[i1], pb2 = rB[i2], pb3 = rB[i3];
#define DP_STEP(e0, e1, e2, e3, tt)                                   \
    {                                                                 \
        const float ls = s_lse[tt];                                   \
        float prev = __shfl_up(a3, 1, 64);                            \
        if (lane == 0) prev = NEG_INF;                                \
        const float n0 = ((e0) - ls) + lae(a0, prev);                 \
        const float n1 = ((e1) - ls) + lae(a1, a0);                   \
        const float n2 = ((e2) - ls) + lae(a2, a1);                   \
        const float n3 = ((e3) - ls) + lae(a3, a2);                   \
        a0 = n0; a1 = n1; a2 = n2; a3 = n3;                           \
    }
    int t = 1;
    while (t < T_FRAMES) {
        DP_STEP(pa0, pa1, pa2, pa3, t);
        {
            const int tn = (t + 2 < T_FRAMES) ? (t + 2) : (T_FRAMES - 1);
            const float* r = xb + (size_t)tn * BATCH * CVOC;
            pa0 = r[i0]; pa1 = r[i1]; pa2 = r[i2]; pa3 = r[i3];
        }
        ++t;
        if (t >= T_FRAMES) break;
        DP_STEP(pb0, pb1, pb2, pb3, t);
        {
            const int tn = (t + 2 < T_FRAMES) ? (t + 2) : (T_FRAMES - 1);
            const float* r = xb + (size_t)tn * BATCH * CVOC;
            pb0 = r[i0]; pb1 = r[i1]; pb2 = r[i2]; pb3 = r[i3];
        }
        ++t;
    }
#undef DP_STEP
    const float resv = __shfl(a3, 49, 64);
    if (lane == 0) part[b] = -resv;
}

extern "C" void kernel_launch(void* const* d_in, const int* in_sizes, int n_in,
                              void* d_out, int out_size, void* d_ws, size_t ws_size,
                              hipStream_t stream) {
    const float* x = (const float*)d_in[0];        // [T, B, C] float32
    const int* targets = (const int*)d_in[1];      // [B, L] int32
    float* out = (float*)d_out;

    const size_t emit_bytes = (size_t)BATCH * T_FRAMES * EPAD * sizeof(_Float16); // 51.2 MB
    // fast path needs slack past emit for dp's one-row (400 B) over-read
    if (ws_size >= emit_bytes + 8192) {
        _Float16* emit = (_Float16*)d_ws;
        float* part = (float*)((char*)d_ws + emit_bytes + 4096);
        emit_kernel<<<T_FRAMES * BATCH / 16, 256, 0, stream>>>(x, targets, emit);
        dp_kernel<<<BATCH, 64, 0, stream>>>(emit, part);
        reduce_kernel<<<1, 64, 0, stream>>>(part, out);
    } else {
        float* lse = (float*)d_ws;
        float* part = lse + (size_t)BATCH * T_FRAMES;
        lse_kernel<<<T_FRAMES * BATCH / 4, 256, 0, stream>>>(x, lse);
        dp_slow_kernel<<<BATCH, 64, 0, stream>>>(x, targets, lse, part);
        reduce_kernel<<<1, 64, 0, stream>>>(part, out);
    }
}

// Round 3
// 237.992 us; speedup vs baseline: 1.1836x; 1.1836x over previous
//
#include <hip/hip_runtime.h>

// T=2000 frames, B=64 batch, C=256 vocab, L=200 targets.
#define T_FRAMES 2000
#define BATCH    64
#define CVOC     256
#define LTGT     200
#define EPAD     200                  // emit row stride in HALVES (400 B, dense)
#define SEG      20                   // dp: rows per register segment (r5-proven)
#define NSEGH    50                   // SEG*NSEGH = 1000 steps per direction
#define TSPLIT   999                  // forward holds alpha after step t=999
#define NEG_INF  (-1e30f)
#define INV_LN2  1.4426950408889634f
#define LN2      0.6931471805599453f
// emit stores PLAIN fp16 probability p = exp(x - lse). p >= ~e^-13 so no fp16
// flush-to-zero; occasional subnormals (p < 6.1e-5) lose 1-3 mantissa bits —
// irrelevant vs the 2.16e+02 absmax threshold. No storage scale, no descale
// multiplies in the DP step (round-2 post-mortem: dp is issue-bound).

#if __has_builtin(__builtin_amdgcn_exp2f)
__device__ __forceinline__ float fexp2(float x) { return __builtin_amdgcn_exp2f(x); }
#else
__device__ __forceinline__ float fexp2(float x) { return exp2f(x); }
#endif
#if __has_builtin(__builtin_amdgcn_logf)
__device__ __forceinline__ float flog2(float x) { return __builtin_amdgcn_logf(x); }
#else
__device__ __forceinline__ float flog2(float x) { return log2f(x); }
#endif

// 4 packed fp16 emissions, 8-byte aligned so loads are global_load_dwordx2.
struct __align__(8) H4 { _Float16 x, y, z, w; };

// ---------------------------------------------------------------------------
// DPP helpers.
// ---------------------------------------------------------------------------
// wave_shr:1, 0-fill lane 0 — lane i <- lane i-1 (left neighbor).
__device__ __forceinline__ float dpp_shr1_zero(float v) {
    return __int_as_float(__builtin_amdgcn_update_dpp(
        0, __float_as_int(v), 0x138, 0xF, 0xF, true));
}
__device__ __forceinline__ int dpp_shr1_zero_i(int v) {
    return __builtin_amdgcn_update_dpp(0, v, 0x138, 0xF, 0xF, true);
}
// wave_shl:1, 0-fill lane 63 — lane i <- lane i+1 (right neighbor).
__device__ __forceinline__ float dpp_shl1_zero(float v) {
    return __int_as_float(__builtin_amdgcn_update_dpp(
        0, __float_as_int(v), 0x130, 0xF, 0xF, true));
}
__device__ __forceinline__ int dpp_shl1_zero_i(int v) {
    return __builtin_amdgcn_update_dpp(0, v, 0x130, 0xF, 0xF, true);
}
template <int CTRL, int RMASK>
__device__ __forceinline__ float dpp_term(float v) {
    return __int_as_float(__builtin_amdgcn_update_dpp(
        0, __float_as_int(v), CTRL, RMASK, 0xF, true));
}
// wave max/sum via DPP (0-fill is fine: used on non-negative or as a
// stabilizer where exactness of the max is not required), bcast via lane 63.
__device__ __forceinline__ float wave_max(float v) {
    v = fmaxf(v, dpp_term<0x111, 0xF>(v));   // row_shr:1
    v = fmaxf(v, dpp_term<0x112, 0xF>(v));   // row_shr:2
    v = fmaxf(v, dpp_term<0x114, 0xF>(v));   // row_shr:4
    v = fmaxf(v, dpp_term<0x118, 0xF>(v));   // row_shr:8
    v = fmaxf(v, dpp_term<0x142, 0xA>(v));   // row_bcast:15 -> rows 1,3
    v = fmaxf(v, dpp_term<0x143, 0xC>(v));   // row_bcast:31 -> rows 2,3
    return __int_as_float(__builtin_amdgcn_readlane(__float_as_int(v), 63));
}
__device__ __forceinline__ float wave_sum(float v) {
    v += dpp_term<0x111, 0xF>(v);
    v += dpp_term<0x112, 0xF>(v);
    v += dpp_term<0x114, 0xF>(v);
    v += dpp_term<0x118, 0xF>(v);
    v += dpp_term<0x142, 0xA>(v);
    v += dpp_term<0x143, 0xC>(v);
    return __int_as_float(__builtin_amdgcn_readlane(__float_as_int(v), 63));
}

// ---------------------------------------------------------------------------
// Kernel 1: fused log-softmax + target gather -> plain fp16 probabilities.
// ---------------------------------------------------------------------------
__global__ __launch_bounds__(256) void emit_kernel(const float* __restrict__ x,
                                                   const int* __restrict__ targets,
                                                   _Float16* __restrict__ emit) {
    __shared__ float s[16][CVOC];                // 16 KB
    const int w = threadIdx.x >> 6;
    const int lane = threadIdx.x & 63;
    const int r0 = blockIdx.x * 16 + w * 4;      // this wave's 4 rows (r = t*64+b)
    const int li = (lane < 50) ? lane : 49;

    float4 v[4];
#pragma unroll
    for (int k = 0; k < 4; ++k)
        v[k] = ((const float4*)(x + (size_t)(r0 + k) * CVOC))[lane];
    int4 tg[4];
#pragma unroll
    for (int k = 0; k < 4; ++k)
        tg[k] = ((const int4*)(targets + ((r0 + k) & 63) * LTGT))[li];

    float lse2[4];
#pragma unroll
    for (int k = 0; k < 4; ++k) {
        v[k].x *= INV_LN2; v[k].y *= INV_LN2; v[k].z *= INV_LN2; v[k].w *= INV_LN2;
        float m = fmaxf(fmaxf(v[k].x, v[k].y), fmaxf(v[k].z, v[k].w));
        m = wave_max(m);                         // m >= true max suffices (stabilizer)
        float ss = fexp2(v[k].x - m) + fexp2(v[k].y - m) +
                   fexp2(v[k].z - m) + fexp2(v[k].w - m);
        ss = wave_sum(ss);
        lse2[k] = m + flog2(ss);
        ((float4*)&s[w * 4 + k][lane * 4])[0] = v[k];   // same-wave staging
    }

#pragma unroll
    for (int k = 0; k < 4; ++k) {
        if (lane < 50) {
            const int r = r0 + k;
            const int t = r >> 6;
            const int b = r & 63;
            H4 h;
            h.x = (_Float16)fexp2(s[w * 4 + k][tg[k].x] - lse2[k]);
            h.y = (_Float16)fexp2(s[w * 4 + k][tg[k].y] - lse2[k]);
            h.z = (_Float16)fexp2(s[w * 4 + k][tg[k].z] - lse2[k]);
            h.w = (_Float16)fexp2(s[w * 4 + k][tg[k].w] - lse2[k]);
            ((H4*)(emit + ((size_t)b * T_FRAMES + t) * EPAD))[lane] = h;
        }
    }
}

// ---------------------------------------------------------------------------
// Kernel 2: forward/backward split DP (serial length halved: 1000 steps each).
// answer[b] = (M_1999...M_1 a0)[199] = v . a999 with
//   a999 = M_999...M_1 a0            (forward blocks,  64)
//   v^T  = unit_199^T M_1999...M_1000 (backward blocks, 64)
// Forward step:  z'_l = e_l (z_l + z_{l-1})             (shr DPP carry)
// Backward step: w_l = v_l e_l ; v'_l = w_l + w_{l+1}   (shl DPP carry)
// Per-lane power-of-2 scale A, renorm every 4 steps (r5-proven dynamics:
// plain probabilities, pure decay). Lanes >= 50 in backward hold identically
// zero v (only inflow is w0 = v0*e0 = 0), so the shl boundary into lane 49 is
// clean without masking.
// ---------------------------------------------------------------------------
__device__ __forceinline__ H4 ld_row(const _Float16* base, int t, int fi) {
    return ((const H4*)(base + (size_t)t * EPAD))[fi];
}

// Forward renorm: inactive lanes adopt LEFT neighbor's scale (front moves right).
__device__ __forceinline__ void renormF(float& z0, float& z1, float& z2, float& z3,
                                        int& A) {
    const float m4 = fmaxf(fmaxf(z0, z1), fmaxf(z2, z3));
    const int Ap = dpp_shr1_zero_i(A);
    const bool act = (m4 > 0.0f);
    const int sh = act ? (127 - ((__float_as_int(m4) >> 23) & 255)) : 0;
    z0 = ldexpf(z0, sh); z1 = ldexpf(z1, sh);
    z2 = ldexpf(z2, sh); z3 = ldexpf(z3, sh);
    A = act ? (A - sh) : Ap;
}
// Backward renorm: inactive lanes adopt RIGHT neighbor's scale (front moves left).
__device__ __forceinline__ void renormB(float& z0, float& z1, float& z2, float& z3,
                                        int& A) {
    const float m4 = fmaxf(fmaxf(z0, z1), fmaxf(z2, z3));
    const int Ap = dpp_shl1_zero_i(A);
    const bool act = (m4 > 0.0f);
    const int sh = act ? (127 - ((__float_as_int(m4) >> 23) & 255)) : 0;
    z0 = ldexpf(z0, sh); z1 = ldexpf(z1, sh);
    z2 = ldexpf(z2, sh); z3 = ldexpf(z3, sh);
    A = act ? (A - sh) : Ap;
}

__global__ __launch_bounds__(64, 1) void dp2_kernel(const _Float16* __restrict__ emit,
                                                    float4* __restrict__ fz,
                                                    int* __restrict__ fA,
                                                    float4* __restrict__ bz,
                                                    int* __restrict__ bA) {
    const int bid = blockIdx.x;
    const bool bwd = bid >= BATCH;
    const int b = bwd ? (bid - BATCH) : bid;
    const int lane = threadIdx.x;
    const _Float16* base = emit + (size_t)b * T_FRAMES * EPAD;
    const int fi = (lane < 50) ? lane : 49;

    H4 ebA[SEG], ebB[SEG];

    if (!bwd) {
        // ---------------- forward: steps t = 1..1000, capture at t = 999 ----
        const float e00 = (float)base[0];
        float z0 = (lane == 0) ? e00 : 0.0f;
        float z1 = 0.0f, z2 = 0.0f, z3 = 0.0f;
        int A = 0;
        renormF(z0, z1, z2, z3, A);

        float r0 = 0.0f, r1 = 0.0f, r2 = 0.0f, r3 = 0.0f;
        int rA = 0;

#pragma unroll
        for (int j = 0; j < SEG; ++j)
            ebA[j] = ld_row(base, 1 + j, fi);
        __builtin_amdgcn_sched_barrier(0);

#define DPF_STEP(e, tcur, j)                                          \
    {                                                                 \
        const float p  = dpp_shr1_zero(z3);                           \
        const int   Ap = dpp_shr1_zero_i(A);                          \
        const float pe = ldexpf(p, Ap - A);                           \
        const float e0 = (float)(e).x;                                \
        const float e1 = (float)(e).y;                                \
        const float e2 = (float)(e).z;                                \
        const float e3 = (float)(e).w;                                \
        const float n0 = e0 * (z0 + pe);                              \
        const float n1 = e1 * (z1 + z0);                              \
        const float n2 = e2 * (z2 + z1);                              \
        const float n3 = e3 * (z3 + z2);                              \
        z0 = n0; z1 = n1; z2 = n2; z3 = n3;                           \
        if ((tcur) == TSPLIT) { r0 = z0; r1 = z1; r2 = z2; r3 = z3; rA = A; } \
        if (((j) & 3) == 3) renormF(z0, z1, z2, z3, A);               \
    }

        for (int sp = 0; sp < NSEGH; sp += 2) {
#pragma unroll
            for (int j = 0; j < SEG; ++j)
                ebB[j] = ld_row(base, 1 + (sp + 1) * SEG + j, fi);
            __builtin_amdgcn_sched_barrier(0);
#pragma unroll
            for (int j = 0; j < SEG; ++j)
                DPF_STEP(ebA[j], 1 + sp * SEG + j, j);
            __builtin_amdgcn_sched_barrier(0);
            if (sp + 2 < NSEGH) {
#pragma unroll
                for (int j = 0; j < SEG; ++j)
                    ebA[j] = ld_row(base, 1 + (sp + 2) * SEG + j, fi);
                __builtin_amdgcn_sched_barrier(0);
            }
#pragma unroll
            for (int j = 0; j < SEG; ++j)
                DPF_STEP(ebB[j], 1 + (sp + 1) * SEG + j, j);
            __builtin_amdgcn_sched_barrier(0);
        }
#undef DPF_STEP

        fz[b * 64 + lane] = make_float4(r0, r1, r2, r3);
        fA[b * 64 + lane] = rA;
    } else {
        // ---------------- backward: steps t = 1999 down to 1000 -------------
        float z0 = 0.0f, z1 = 0.0f, z2 = 0.0f;
        float z3 = (lane == 49) ? 1.0f : 0.0f;   // unit at l = 199
        int A = 0;

#pragma unroll
        for (int j = 0; j < SEG; ++j)
            ebA[j] = ld_row(base, 1999 - j, fi);
        __builtin_amdgcn_sched_barrier(0);

#define DPB_STEP(e, j)                                                \
    {                                                                 \
        const float e0 = (float)(e).x;                                \
        const float e1 = (float)(e).y;                                \
        const float e2 = (float)(e).z;                                \
        const float e3 = (float)(e).w;                                \
        const float w0 = z0 * e0;                                     \
        const float w1 = z1 * e1;                                     \
        const float w2 = z2 * e2;                                     \
        const float w3 = z3 * e3;                                     \
        const float q  = dpp_shl1_zero(w0);                           \
        const int   Aq = dpp_shl1_zero_i(A);                          \
        const float pe = ldexpf(q, Aq - A);                           \
        z0 = w0 + w1; z1 = w1 + w2; z2 = w2 + w3; z3 = w3 + pe;       \
        if (((j) & 3) == 3) renormB(z0, z1, z2, z3, A);               \
    }

        for (int sp = 0; sp < NSEGH; sp += 2) {
#pragma unroll
            for (int j = 0; j < SEG; ++j)
                ebB[j] = ld_row(base, 1999 - ((sp + 1) * SEG + j), fi);
            __builtin_amdgcn_sched_barrier(0);
#pragma unroll
            for (int j = 0; j < SEG; ++j)
                DPB_STEP(ebA[j], j);
            __builtin_amdgcn_sched_barrier(0);
            if (sp + 2 < NSEGH) {
#pragma unroll
                for (int j = 0; j < SEG; ++j)
                    ebA[j] = ld_row(base, 1999 - ((sp + 2) * SEG + j), fi);
                __builtin_amdgcn_sched_barrier(0);
            }
#pragma unroll
            for (int j = 0; j < SEG; ++j)
                DPB_STEP(ebB[j], j);
            __builtin_amdgcn_sched_barrier(0);
        }
#undef DPB_STEP

        bz[b * 64 + lane] = make_float4(z0, z1, z2, z3);
        bA[b * 64 + lane] = A;
    }
}

// ---------------------------------------------------------------------------
// Kernel 3: combine — scaled dot of alpha_999 and the backward row, logsumexp
// across lanes (shfl-based: values are negative, DPP 0-fill max is unusable).
// ---------------------------------------------------------------------------
__global__ __launch_bounds__(64) void combine_kernel(const float4* __restrict__ fz,
                                                     const int* __restrict__ fA,
                                                     const float4* __restrict__ bz,
                                                     const int* __restrict__ bA,
                                                     float* __restrict__ part) {
    const int b = blockIdx.x;
    const int lane = threadIdx.x;
    const float4 f = fz[b * 64 + lane];
    const float4 g = bz[b * 64 + lane];
    const float s = f.x * g.x + f.y * g.y + f.z * g.z + f.w * g.w;
    float tl = (lane < 50 && s > 0.0f)
                   ? flog2(s) + (float)(fA[b * 64 + lane] + bA[b * 64 + lane])
                   : -3.0e38f;
    float m = tl;
#pragma unroll
    for (int d = 1; d < 64; d <<= 1) m = fmaxf(m, __shfl_xor(m, d, 64));
    float p = fexp2(tl - m);
#pragma unroll
    for (int d = 1; d < 64; d <<= 1) p += __shfl_xor(p, d, 64);
    if (lane == 0) part[b] = -(m + flog2(p)) * LN2;   // back to nats
}

// ---------------------------------------------------------------------------
// Kernel 4: mean over the 64 per-batch NLLs.
// ---------------------------------------------------------------------------
__global__ __launch_bounds__(64) void reduce_kernel(const float* __restrict__ part,
                                                    float* __restrict__ out) {
    float v = part[threadIdx.x];
#pragma unroll
    for (int s = 1; s < 64; s <<= 1) v += __shfl_xor(v, s, 64);
    if (threadIdx.x == 0) out[0] = v * (1.0f / BATCH);
}

// ===========================================================================
// Fallback path (round-1, natural-log domain, verified) if ws too small.
// ===========================================================================
__device__ __forceinline__ float lae(float a, float b) {
    float m = fmaxf(a, b);
    float d = fminf(a, b) - m;
    return m + __logf(1.0f + __expf(d));
}

__global__ __launch_bounds__(256) void lse_kernel(const float* __restrict__ x,
                                                  float* __restrict__ lse) {
    const int wave = threadIdx.x >> 6;
    const int lane = threadIdx.x & 63;
    const int r = blockIdx.x * 4 + wave;
    float4 v = ((const float4*)(x + (size_t)r * CVOC))[lane];
    float m = fmaxf(fmaxf(v.x, v.y), fmaxf(v.z, v.w));
#pragma unroll
    for (int s = 1; s < 64; s <<= 1) m = fmaxf(m, __shfl_xor(m, s, 64));
    float ssum = __expf(v.x - m) + __expf(v.y - m) + __expf(v.z - m) + __expf(v.w - m);
#pragma unroll
    for (int s = 1; s < 64; s <<= 1) ssum += __shfl_xor(ssum, s, 64);
    if (lane == 0) {
        const int t = r >> 6;
        const int b = r & 63;
        lse[b * T_FRAMES + t] = m + __logf(ssum);
    }
}

__global__ __launch_bounds__(64) void dp_slow_kernel(const float* __restrict__ x,
                                                     const int* __restrict__ targets,
                                                     const float* __restrict__ lse,
                                                     float* __restrict__ part) {
    __shared__ float s_lse[T_FRAMES];
    const int b = blockIdx.x;
    const int lane = threadIdx.x;
    for (int i = lane; i < T_FRAMES; i += 64) s_lse[i] = lse[b * T_FRAMES + i];
    const int* tg = targets + b * LTGT;
    const int l0 = lane * 4;
    const int i0 = tg[(l0 + 0 < LTGT) ? (l0 + 0) : (LTGT - 1)];
    const int i1 = tg[(l0 + 1 < LTGT) ? (l0 + 1) : (LTGT - 1)];
    const int i2 = tg[(l0 + 2 < LTGT) ? (l0 + 2) : (LTGT - 1)];
    const int i3 = tg[(l0 + 3 < LTGT) ? (l0 + 3) : (LTGT - 1)];
    const float* xb = x + b * CVOC;
    __syncthreads();
    float a0 = (lane == 0) ? (xb[i0] - s_lse[0]) : NEG_INF;
    float a1 = NEG_INF, a2 = NEG_INF, a3 = NEG_INF;
    const float* rA = xb + (size_t)1 * BATCH * CVOC;
    float pa0 = rA[i0], pa1 = rA[i1], pa2 = rA[i2], pa3 = rA[i3];
    const float* rB = xb + (size_t)2 * BATCH * CVOC;
    float pb0 = rB[i0], pb1 = rB[i1], pb2 = rB[i2], pb3 = rB[i3];
#define DP_STEP(e0, e1, e2, e3, tt)                                   \
    {                                                                 \
        const float ls = s_lse[tt];                                   \
        float prev = __shfl_up(a3, 1, 64);                            \
        if (lane == 0) prev = NEG_INF;                                \
        const float n0 = ((e0) - ls) + lae(a0, prev);                 \
        const float n1 = ((e1) - ls) + lae(a1, a0);                   \
        const float n2 = ((e2) - ls) + lae(a2, a1);                   \
        const float n3 = ((e3) - ls) + lae(a3, a2);                   \
        a0 = n0; a1 = n1; a2 = n2; a3 = n3;                           \
    }
    int t = 1;
    while (t < T_FRAMES) {
        DP_STEP(pa0, pa1, pa2, pa3, t);
        {
            const int tn = (t + 2 < T_FRAMES) ? (t + 2) : (T_FRAMES - 1);
            const float* r = xb + (size_t)tn * BATCH * CVOC;
            pa0 = r[i0]; pa1 = r[i1]; pa2 = r[i2]; pa3 = r[i3];
        }
        ++t;
        if (t >= T_FRAMES) break;
        DP_STEP(pb0, pb1, pb2, pb3, t);
        {
            const int tn = (t + 2 < T_FRAMES) ? (t + 2) : (T_FRAMES - 1);
            const float* r = xb + (size_t)tn * BATCH * CVOC;
            pb0 = r[i0]; pb1 = r[i1]; pb2 = r[i2]; pb3 = r[i3];
        }
        ++t;
    }
#undef DP_STEP
    const float resv = __shfl(a3, 49, 64);
    if (lane == 0) part[b] = -resv;
}

extern "C" void kernel_launch(void* const* d_in, const int* in_sizes, int n_in,
                              void* d_out, int out_size, void* d_ws, size_t ws_size,
                              hipStream_t stream) {
    const float* x = (const float*)d_in[0];        // [T, B, C] float32
    const int* targets = (const int*)d_in[1];      // [B, L] int32
    float* out = (float*)d_out;

    const size_t emit_bytes = (size_t)BATCH * T_FRAMES * EPAD * sizeof(_Float16); // 51.2 MB
    const size_t off_part = emit_bytes + 4096;
    const size_t off_fz   = emit_bytes + 8192;               // 16B aligned
    const size_t off_fA   = off_fz + (size_t)BATCH * 64 * 16;
    const size_t off_bz   = off_fA + (size_t)BATCH * 64 * 4;
    const size_t off_bA   = off_bz + (size_t)BATCH * 64 * 16;
    const size_t need     = off_bA + (size_t)BATCH * 64 * 4 + 4096;

    if (ws_size >= need) {
        _Float16* emit = (_Float16*)d_ws;
        float*  part = (float*)((char*)d_ws + off_part);
        float4* fz   = (float4*)((char*)d_ws + off_fz);
        int*    fAi  = (int*)((char*)d_ws + off_fA);
        float4* bz   = (float4*)((char*)d_ws + off_bz);
        int*    bAi  = (int*)((char*)d_ws + off_bA);
        emit_kernel<<<T_FRAMES * BATCH / 16, 256, 0, stream>>>(x, targets, emit);
        dp2_kernel<<<2 * BATCH, 64, 0, stream>>>(emit, fz, fAi, bz, bAi);
        combine_kernel<<<BATCH, 64, 0, stream>>>(fz, fAi, bz, bAi, part);
        reduce_kernel<<<1, 64, 0, stream>>>(part, out);
    } else {
        float* lse = (float*)d_ws;
        float* part = lse + (size_t)BATCH * T_FRAMES;
        lse_kernel<<<T_FRAMES * BATCH / 4, 256, 0, stream>>>(x, lse);
        dp_slow_kernel<<<BATCH, 64, 0, stream>>>(x, targets, lse, part);
        reduce_kernel<<<1, 64, 0, stream>>>(part, out);
    }
}